// Round 19
// baseline (1540.251 us; speedup 1.0000x reference)
//
#include <hip/hip_runtime.h>

#define DEV __device__ __forceinline__

typedef __attribute__((ext_vector_type(8))) short bf16x8;
typedef __attribute__((ext_vector_type(4))) float f32x4;

typedef const __attribute__((address_space(1))) void* gsrc_t;
typedef __attribute__((address_space(3))) void* gdst_t;

DEV void gld16(const void* g, void* l){ __builtin_amdgcn_global_load_lds((gsrc_t)g,(gdst_t)l,16,0,0); }

DEV unsigned short f2bf(float f){
  union { float f; unsigned int u; } x; x.f = f;
  unsigned int u = x.u;
  return (unsigned short)((u + 0x7fffu + ((u >> 16) & 1u)) >> 16);
}
DEV unsigned long long pack4bf(float a, float b, float c, float d){
  return (unsigned long long)f2bf(a)
       | ((unsigned long long)f2bf(b) << 16)
       | ((unsigned long long)f2bf(c) << 32)
       | ((unsigned long long)f2bf(d) << 48);
}
DEV float gelu_t(float x){
  float u = 0.7978845608028654f * (x + 0.044715f * x * x * x);
  return 0.5f * x * (1.0f + tanhf(u));
}
DEV float sigmoidf_(float x){ return 1.0f / (1.0f + expf(-x)); }

DEV void BAR_TOP(){ __builtin_amdgcn_s_barrier(); asm volatile("" ::: "memory"); }
DEV void BAR_END(){
  __builtin_amdgcn_sched_barrier(0);
  asm volatile("s_waitcnt lgkmcnt(0)" ::: "memory");
  __builtin_amdgcn_s_barrier();
  asm volatile("" ::: "memory");
}

// ---------------- merged prep: dec_w transpose (4000) + 3x 512^2 transpose (192)
// + embedding gather (2048 blocks, 2 rows each). Block 0 zeroes ctl flags.
__global__ __launch_bounds__(256) void kPrep(const float* __restrict__ dec_w,
                                             unsigned short* __restrict__ dec_wT,
                                             const float* __restrict__ s0, const float* __restrict__ s1,
                                             const float* __restrict__ s2,
                                             unsigned short* __restrict__ d0, unsigned short* __restrict__ d1,
                                             unsigned short* __restrict__ d2,
                                             const int* __restrict__ ids,
                                             const float* __restrict__ embed,
                                             unsigned short* __restrict__ E,
                                             unsigned int* __restrict__ flag){
  __shared__ float t[64][65];
  const int bid = blockIdx.x, tid = threadIdx.x;
  if (bid == 0 && tid < 16) flag[tid] = 0u;
  if (bid < 4000){
    int n0 = (bid % 500) * 64, k0 = (bid / 500) * 64;
    #pragma unroll
    for (int i = 0; i < 16; i++){
      int idx = i * 256 + tid; int r = idx >> 6, c = idx & 63;
      t[r][c] = dec_w[(size_t)(k0 + r) * 32000 + n0 + c];
    }
    __syncthreads();
    #pragma unroll
    for (int i = 0; i < 16; i++){
      int idx = i * 256 + tid; int r = idx >> 6, c = idx & 63;
      dec_wT[(size_t)(n0 + r) * 512 + k0 + c] = f2bf(t[c][r]);
    }
  } else if (bid < 4192){
    int rel = bid - 4000;
    int z = rel >> 6, rem = rel & 63;
    const float* W = (z == 0) ? s0 : (z == 1) ? s1 : s2;
    unsigned short* D = (z == 0) ? d0 : (z == 1) ? d1 : d2;
    int n0 = (rem & 7) * 64, k0 = (rem >> 3) * 64;
    #pragma unroll
    for (int i = 0; i < 16; i++){
      int idx = i * 256 + tid; int r = idx >> 6, c = idx & 63;
      t[r][c] = W[(size_t)(k0 + r) * 512 + n0 + c];
    }
    __syncthreads();
    #pragma unroll
    for (int i = 0; i < 16; i++){
      int idx = i * 256 + tid; int r = idx >> 6, c = idx & 63;
      D[(size_t)(n0 + r) * 512 + k0 + c] = f2bf(t[c][r]);
    }
  } else {
    int idx = bid - 4192;                 // 0..2047, two rows per block
    int row = idx * 2 + (tid >> 7);
    int t2  = tid & 127;
    int id = ids[row];
    float4 v = ((const float4*)(embed + (size_t)id * 512))[t2];
    *(unsigned long long*)(E + (size_t)row * 512 + t2 * 4) = pack4bf(v.x, v.y, v.z, v.w);
  }
}

// ---------------- fused 16x512 GEMM + (gelu) + LN + (ACT update) + pooling partials
// Grid 256 blocks (1/CU). A-tile staged by wave 0 (1 gld16); B by all (4 gld16).
template<int ENC>
__global__ __launch_bounds__(512) void kGemmLN(
    const unsigned short* __restrict__ A, const unsigned short* __restrict__ BT,
    const float* __restrict__ bias, const float* __restrict__ lns, const float* __restrict__ lnb,
    const float* __restrict__ hw, const float* __restrict__ hb,
    float* __restrict__ st, unsigned short* __restrict__ stb,
    float* __restrict__ part, float* __restrict__ halt_p, float* __restrict__ halted){
  __shared__ alignas(16) unsigned short lA[2][16 * 32];
  __shared__ alignas(16) unsigned short lB[2][512 * 32];
  __shared__ float pS[8][16], pQ[8][16], pH[8][16];
  __shared__ float sMean[16], sRs[16], sFac[16];
  const int tid = threadIdx.x, w = tid >> 6, lane = tid & 63;
  const int q = lane >> 4, c = lane & 15, lk8 = q * 8;
  const int r0 = blockIdx.x * 16;
  const int br = tid >> 2, bk = (tid & 3) * 8;
  f32x4 acc[4] = {};

  auto STAGE = [&](int buf, int k0){
    if (w == 0)
      gld16(A + (size_t)(r0 + (lane >> 2)) * 512 + k0 + (lane & 3) * 8, &lA[buf][lane * 8]);
    #pragma unroll
    for (int i = 0; i < 4; i++)
      gld16(BT + (size_t)(i * 128 + br) * 512 + k0 + bk, &lB[buf][(i * 512 + tid) * 8]);
  };

  STAGE(0, 0);
  #pragma unroll
  for (int t = 0; t < 16; t++){
    if (t < 15){
      STAGE((t + 1) & 1, (t + 1) * 32);
      if (w == 0) asm volatile("s_waitcnt vmcnt(5)" ::: "memory");
      else        asm volatile("s_waitcnt vmcnt(4)" ::: "memory");
    } else {
      asm volatile("s_waitcnt vmcnt(0)" ::: "memory");
    }
    BAR_TOP();
    bf16x8 af = *(const bf16x8*)&lA[t & 1][c * 32 + lk8];
    bf16x8 bfv[4];
    #pragma unroll
    for (int n = 0; n < 4; n++)
      bfv[n] = *(const bf16x8*)&lB[t & 1][(w * 64 + n * 16 + c) * 32 + lk8];
    #pragma unroll
    for (int n = 0; n < 4; n++)
      acc[n] = __builtin_amdgcn_mfma_f32_16x16x32_bf16(af, bfv[n], acc[n], 0, 0, 0);
    BAR_END();
  }

  // ---- bias (+gelu)
  #pragma unroll
  for (int n = 0; n < 4; n++){
    float bcol = bias[w * 64 + n * 16 + c];
    #pragma unroll
    for (int r = 0; r < 4; r++){
      float v = acc[n][r] + bcol;
      if (ENC) v = gelu_t(v);
      acc[n][r] = v;
    }
  }
  // ---- LN stats (16 rows)
  float rS[4], rQ[4];
  #pragma unroll
  for (int r = 0; r < 4; r++){
    float s = 0.f, s2 = 0.f;
    #pragma unroll
    for (int n = 0; n < 4; n++){ float v = acc[n][r]; s += v; s2 += v * v; }
    rS[r] = s; rQ[r] = s2;
  }
  #pragma unroll
  for (int mask = 1; mask < 16; mask <<= 1)
    #pragma unroll
    for (int r = 0; r < 4; r++){
      rS[r] += __shfl_xor(rS[r], mask);
      rQ[r] += __shfl_xor(rQ[r], mask);
    }
  if (c == 0)
    #pragma unroll
    for (int r = 0; r < 4; r++){ pS[w][q * 4 + r] = rS[r]; pQ[w][q * 4 + r] = rQ[r]; }
  __syncthreads();
  if (tid < 16){
    float s = 0.f, s2 = 0.f;
    #pragma unroll
    for (int v = 0; v < 8; v++){ s += pS[v][tid]; s2 += pQ[v][tid]; }
    float mean = s * (1.f / 512.f);
    float var  = s2 * (1.f / 512.f) - mean * mean;
    sMean[tid] = mean; sRs[tid] = rsqrtf(var + 1e-5f);
    if (ENC){ halt_p[r0 + tid] = 0.f; halted[r0 + tid] = 0.f; }
  }
  __syncthreads();
  float lnsv[4], lnbv[4];
  #pragma unroll
  for (int n = 0; n < 4; n++){ lnsv[n] = lns[w * 64 + n * 16 + c]; lnbv[n] = lnb[w * 64 + n * 16 + c]; }
  #pragma unroll
  for (int r = 0; r < 4; r++){
    int row = q * 4 + r;
    float mu = sMean[row], rs = sRs[row];
    #pragma unroll
    for (int n = 0; n < 4; n++)
      acc[n][r] = (acc[n][r] - mu) * rs * lnsv[n] + lnbv[n];
  }

  float sold[4][4];
  if (!ENC){
    float hwv[4];
    #pragma unroll
    for (int n = 0; n < 4; n++) hwv[n] = hw[w * 64 + n * 16 + c];
    #pragma unroll
    for (int r = 0; r < 4; r++){
      int row = q * 4 + r;
      #pragma unroll
      for (int n = 0; n < 4; n++)
        sold[n][r] = st[(size_t)(r0 + row) * 512 + w * 64 + n * 16 + c];
    }
    float rH[4];
    #pragma unroll
    for (int r = 0; r < 4; r++){
      float d = 0.f;
      #pragma unroll
      for (int n = 0; n < 4; n++) d += (sold[n][r] + acc[n][r]) * hwv[n];
      rH[r] = d;
    }
    #pragma unroll
    for (int mask = 1; mask < 16; mask <<= 1)
      #pragma unroll
      for (int r = 0; r < 4; r++) rH[r] += __shfl_xor(rH[r], mask);
    if (c == 0)
      #pragma unroll
      for (int r = 0; r < 4; r++) pH[w][q * 4 + r] = rH[r];
    __syncthreads();
    if (tid < 16){
      float d = 0.f;
      #pragma unroll
      for (int v = 0; v < 8; v++) d += pH[v][tid];
      float hd = halted[r0 + tid];
      float p  = sigmoidf_(d + hb[0]);
      float hp = halt_p[r0 + tid] + p * (1.f - hd);
      halt_p[r0 + tid] = hp;
      halted[r0 + tid] = (hp > 0.99f) ? 1.f : 0.f;
      sFac[tid] = 1.f - hd;
    }
    __syncthreads();
    #pragma unroll
    for (int r = 0; r < 4; r++){
      float f = sFac[q * 4 + r];
      #pragma unroll
      for (int n = 0; n < 4; n++)
        acc[n][r] = sold[n][r] + f * acc[n][r];
    }
  }

  // ---- write state (fp32 + bf16)
  #pragma unroll
  for (int r = 0; r < 4; r++){
    int row = r0 + q * 4 + r;
    #pragma unroll
    for (int n = 0; n < 4; n++){
      int col = w * 64 + n * 16 + c;
      float v = acc[n][r];
      st [(size_t)row * 512 + col] = v;
      stb[(size_t)row * 512 + col] = f2bf(v);
    }
  }
  // ---- pooled partial sums over this block's 16 rows
  #pragma unroll
  for (int n = 0; n < 4; n++){
    float s = 0.f;
    #pragma unroll
    for (int r = 0; r < 4; r++) s += acc[n][r];
    s += __shfl_xor(s, 16);
    s += __shfl_xor(s, 32);
    if (q == 0) part[(size_t)blockIdx.x * 512 + w * 64 + n * 16 + c] = s;
  }
}

// ---------------- fused GEMM1 + controller: blocks 0..3 = controller (RMW flag publish),
// blocks 4..515 = 64x64 GEMM tiles (K-loop independent of r2; epilogue RMW-spins).
__global__ __launch_bounds__(256) void kGemm64C(const unsigned short* __restrict__ A,
                                                const unsigned short* __restrict__ BT,
                                                float* __restrict__ r2,
                                                unsigned short* __restrict__ C,
                                                const float* __restrict__ part,
                                                const float* __restrict__ idx_w, const float* __restrict__ idx_b,
                                                const float* __restrict__ mu_w, const float* __restrict__ mu_b,
                                                const float* __restrict__ sig_w, const float* __restrict__ sig_b,
                                                const float* __restrict__ pool_table,
                                                const float* __restrict__ w1b, const float* __restrict__ int_b1,
                                                unsigned int* __restrict__ flag,
                                                float* __restrict__ outIdx, int l){
  const int bid = blockIdx.x, tid = threadIdx.x;

  if (bid < 4){
    // ---------------- controller path (256 threads, 2 outputs each; round-10 verified math)
    __shared__ float xs[512], red[512], red2[512], evals[64], sc[4];
    const int b = bid;
    float s0 = 0.f, s1 = 0.f;
    #pragma unroll 8
    for (int c2 = 0; c2 < 64; c2++){
      s0 += part[(size_t)(b * 64 + c2) * 512 + tid];
      s1 += part[(size_t)(b * 64 + c2) * 512 + tid + 256];
    }
    xs[tid] = s0 * (1.0f / 1024.0f);
    xs[tid + 256] = s1 * (1.0f / 1024.0f);
    __syncthreads();
    float a0 = idx_b[tid], a1 = idx_b[tid + 256];
    #pragma unroll 16
    for (int i = 0; i < 512; i++){
      float x = xs[i];
      a0 = fmaf(x, idx_w[(size_t)i * 512 + tid], a0);
      a1 = fmaf(x, idx_w[(size_t)i * 512 + tid + 256], a1);
    }
    float h0 = gelu_t(a0), h1 = gelu_t(a1);
    red[tid]  = h0 * mu_w[tid]  + h1 * mu_w[tid + 256];
    red2[tid] = h0 * sig_w[tid] + h1 * sig_w[tid + 256];
    __syncthreads();
    for (int off2 = 128; off2 > 0; off2 >>= 1){
      if (tid < off2){ red[tid] += red[tid + off2]; red2[tid] += red2[tid + off2]; }
      __syncthreads();
    }
    if (tid == 0){
      float mu = sigmoidf_(red[0] + mu_b[0]);
      float sg = log1pf(expf(red2[0] + sig_b[0])) + 1e-4f;
      float center = mu * 250000.0f;
      int stt = (int)floorf(center - 32.0f);
      stt = stt < 0 ? 0 : (stt > 250000 - 64 ? 250000 - 64 : stt);
      sc[0] = mu; sc[1] = sg; sc[2] = (float)stt;
      outIdx[b * 4 + l] = (float)stt;
    }
    __syncthreads();
    if (tid < 64){
      float pos = (sc[2] + (float)tid) * (1.0f / 250000.0f);
      float z = (pos - sc[0]) / sc[1];
      evals[tid] = expf(-0.5f * z * z);
    }
    __syncthreads();
    if (tid == 0){
      float ws = 0.f;
      for (int j = 0; j < 64; j++) ws += evals[j];
      sc[3] = ws;
    }
    __syncthreads();
    int stt = (int)sc[2];
    float r0v = 0.f, r1v = 0.f;
    #pragma unroll 8
    for (int j = 0; j < 64; j++){
      float e = evals[j];
      r0v = fmaf(e, pool_table[(size_t)(stt + j) * 512 + tid], r0v);
      r1v = fmaf(e, pool_table[(size_t)(stt + j) * 512 + tid + 256], r1v);
    }
    r0v /= sc[3]; r1v /= sc[3];
    __syncthreads();
    xs[tid] = r0v; xs[tid + 256] = r1v;
    __syncthreads();
    float a20 = int_b1[tid], a21 = int_b1[tid + 256];
    #pragma unroll 16
    for (int i = 0; i < 512; i++){
      float x = xs[i];
      a20 = fmaf(x, w1b[(size_t)i * 512 + tid], a20);
      a21 = fmaf(x, w1b[(size_t)i * 512 + tid + 256], a21);
    }
    r2[(size_t)b * 512 + tid] = a20;
    r2[(size_t)b * 512 + tid + 256] = a21;
    __threadfence();
    __syncthreads();
    if (tid == 0)
      __hip_atomic_exchange(&flag[l * 4 + b], 1u, __ATOMIC_RELEASE, __HIP_MEMORY_SCOPE_AGENT);
    return;
  }

  // ---------------- GEMM path: 64x64 tile, measured-best dbuf pipeline
  __shared__ alignas(16) unsigned short lA[2][64 * 32];
  __shared__ alignas(16) unsigned short lB[2][64 * 32];
  const int g = bid - 4;
  const int w = tid >> 6, lane = tid & 63;
  const int q = lane >> 4, c = lane & 15, lk8 = q * 8;
  const int wm = w >> 1, wn = w & 1;
  const int m0 = (g >> 3) * 64, n0 = (g & 7) * 64;
  const int b = g >> 7;                        // batch index (m0 >> 10)
  const int sr = tid >> 2, sk = (tid & 3) * 8;
  f32x4 acc[2][2] = {};

  auto STAGE = [&](int buf, int k0){
    gld16(A  + (size_t)(m0 + sr) * 512 + k0 + sk, &lA[buf][tid * 8]);
    gld16(BT + (size_t)(n0 + sr) * 512 + k0 + sk, &lB[buf][tid * 8]);
  };

  STAGE(0, 0);
  #pragma unroll
  for (int t = 0; t < 16; t++){
    if (t < 15){
      STAGE((t + 1) & 1, (t + 1) * 32);
      asm volatile("s_waitcnt vmcnt(2)" ::: "memory");
    } else {
      asm volatile("s_waitcnt vmcnt(0)" ::: "memory");
    }
    BAR_TOP();
    bf16x8 af[2], bfv[2];
    #pragma unroll
    for (int m = 0; m < 2; m++) af[m]  = *(const bf16x8*)&lA[t & 1][(wm * 32 + m * 16 + c) * 32 + lk8];
    #pragma unroll
    for (int n = 0; n < 2; n++) bfv[n] = *(const bf16x8*)&lB[t & 1][(wn * 32 + n * 16 + c) * 32 + lk8];
    #pragma unroll
    for (int m = 0; m < 2; m++)
      #pragma unroll
      for (int n = 0; n < 2; n++)
        acc[m][n] = __builtin_amdgcn_mfma_f32_16x16x32_bf16(af[m], bfv[n], acc[m][n], 0, 0, 0);
    BAR_END();
  }

  // wait for r2 (RMW acquire at device coherence point; ctl blocks dispatched first)
  if (tid == 0){
    while (__hip_atomic_fetch_add(&flag[l * 4 + b], 0u, __ATOMIC_ACQUIRE,
                                  __HIP_MEMORY_SCOPE_AGENT) == 0u)
      __builtin_amdgcn_s_sleep(16);
  }
  __syncthreads();

  #pragma unroll
  for (int m = 0; m < 2; m++)
    #pragma unroll
    for (int n = 0; n < 2; n++)
      #pragma unroll
      for (int r = 0; r < 4; r++){
        int row = m0 + wm * 32 + m * 16 + q * 4 + r;
        int col = n0 + wn * 32 + n * 16 + c;
        float v = acc[m][n][r] + r2[((row >> 10) << 9) + col];
        C[(size_t)row * 512 + col] = f2bf(gelu_t(v));
      }
}

// ---------------- decoder GEMM v9 (measured best): 128x256, 512 thr, 3 bufs, vmcnt(3),
// one barrier/phase, compiler-scheduled ds_read->MFMA, early STAGE, T2 swizzle, setprio,
// m-inner + bijective XCD swizzle, nontemporal fp32 stores + bias.
__global__ __launch_bounds__(512) void kGemmDec(const unsigned short* __restrict__ A,
                                                const unsigned short* __restrict__ BT,
                                                const float* __restrict__ bias,
                                                float* __restrict__ C){
  __shared__ alignas(16) unsigned short lA[3][128 * 32];   // 8 KB each
  __shared__ alignas(16) unsigned short lB[3][256 * 32];   // 16 KB each
  const int tid = threadIdx.x, w = tid >> 6, lane = tid & 63;
  const int wm = w >> 2, wn = w & 3;           // 2 x 4 wave grid, per-wave 64x64
  const int c = lane & 15, q = lane >> 4;
  const int rk8 = (q ^ ((c >> 1) & 3)) * 8;    // swizzled read chunk (elems)
  int flat = blockIdx.x;                       // 0..3999
  flat = (flat & 7) * 500 + (flat >> 3);       // bijective XCD swizzle (4000 = 8*500)
  const int m0 = (flat & 31) * 128;            // m-inner: 32 consecutive share one B-panel
  const int n0 = (flat >> 5) * 256;
  const int srow  = tid >> 2;                  // 0..127
  const int skoff = ((tid & 3) ^ ((srow >> 1) & 3)) * 8;  // pre-swizzled source chunk
  const int sdst  = srow * 32 + (tid & 3) * 8;            // linear LDS dest
  f32x4 acc[4][4] = {};

  auto STAGE = [&](int buf, int k0){
    gld16(A  + (size_t)(m0 + srow) * 512 + k0 + skoff,       &lA[buf][sdst]);
    gld16(BT + (size_t)(n0 + srow) * 512 + k0 + skoff,       &lB[buf][sdst]);
    gld16(BT + (size_t)(n0 + 128 + srow) * 512 + k0 + skoff, &lB[buf][128 * 32 + sdst]);
  };

  STAGE(0, 0);
  STAGE(1, 32);
  for (int t = 0; t < 16; t++){
    const int buf = t % 3;
    if (t < 15) asm volatile("s_waitcnt vmcnt(3)" ::: "memory");
    else        asm volatile("s_waitcnt vmcnt(0)" ::: "memory");
    __builtin_amdgcn_s_barrier();
    asm volatile("" ::: "memory");
    if (t < 14) STAGE((t + 2) % 3, (t + 2) * 32);   // loads in flight early
    bf16x8 af[4], bfr[4];
    #pragma unroll
    for (int mf = 0; mf < 4; mf++)
      af[mf] = *(const bf16x8*)&lA[buf][(wm * 64 + mf * 16 + c) * 32 + rk8];
    #pragma unroll
    for (int nf = 0; nf < 4; nf++)
      bfr[nf] = *(const bf16x8*)&lB[buf][(wn * 64 + nf * 16 + c) * 32 + rk8];
    // no manual lgkmcnt/sched_barrier: compiler emits fine-grained waits
    __builtin_amdgcn_s_setprio(1);
    #pragma unroll
    for (int mf = 0; mf < 4; mf++)
      #pragma unroll
      for (int nf = 0; nf < 4; nf++)
        acc[mf][nf] = __builtin_amdgcn_mfma_f32_16x16x32_bf16(af[mf], bfr[nf], acc[mf][nf], 0, 0, 0);
    __builtin_amdgcn_s_setprio(0);
  }

  #pragma unroll
  for (int mf = 0; mf < 4; mf++){
    int rbase = m0 + wm * 64 + mf * 16 + q * 4;
    #pragma unroll
    for (int nf = 0; nf < 4; nf++){
      int col = n0 + wn * 64 + nf * 16 + c;
      float bcol = bias[col];
      #pragma unroll
      for (int r = 0; r < 4; r++)
        __builtin_nontemporal_store(acc[mf][nf][r] + bcol,
                                    &C[(size_t)(rbase + r) * 32000 + col]);
    }
  }
}

extern "C" void kernel_launch(void* const* d_in, const int* in_sizes, int n_in,
                              void* d_out, int out_size, void* d_ws, size_t ws_size,
                              hipStream_t stream){
  (void)in_sizes; (void)n_in; (void)out_size; (void)ws_size;
  const int*   ids    = (const int*)  d_in[0];
  const float* embed  = (const float*)d_in[1];
  const float* enc_w  = (const float*)d_in[2];
  const float* enc_b  = (const float*)d_in[3];
  const float* ln_es  = (const float*)d_in[4];
  const float* ln_eb  = (const float*)d_in[5];
  const float* idx_w  = (const float*)d_in[6];
  const float* idx_b  = (const float*)d_in[7];
  const float* mu_w   = (const float*)d_in[8];
  const float* mu_b   = (const float*)d_in[9];
  const float* sig_w  = (const float*)d_in[10];
  const float* sig_b  = (const float*)d_in[11];
  const float* pool_t = (const float*)d_in[12];
  const float* int_w1 = (const float*)d_in[13];
  const float* int_b1 = (const float*)d_in[14];
  const float* int_w2 = (const float*)d_in[15];
  const float* int_b2 = (const float*)d_in[16];
  const float* ln_s   = (const float*)d_in[17];
  const float* ln_b   = (const float*)d_in[18];
  const float* halt_w = (const float*)d_in[19];
  const float* halt_b = (const float*)d_in[20];
  const float* dec_w  = (const float*)d_in[21];
  const float* dec_b  = (const float*)d_in[22];

  char* ws = (char*)d_ws;
  size_t off = 0;
  auto alloc = [&](size_t bytes)->char*{
    char* p = ws + off; off += (bytes + 255) & ~(size_t)255; return p;
  };
  unsigned short* dec_wT  = (unsigned short*)alloc(32000ull * 512 * 2);
  unsigned short* enc_wT  = (unsigned short*)alloc(512ull * 512 * 2);
  unsigned short* w1T     = (unsigned short*)alloc(512ull * 512 * 2);
  unsigned short* w2T     = (unsigned short*)alloc(512ull * 512 * 2);
  unsigned short* bufB    = (unsigned short*)alloc(4096ull * 512 * 2);  // E / G (bf16)
  float*          state   = (float*)alloc(4096ull * 512 * 4);
  unsigned short* state_b = (unsigned short*)alloc(4096ull * 512 * 2);
  float*          part    = (float*)alloc(256ull * 512 * 4);
  float*          r2      = (float*)alloc(4ull * 512 * 4);
  float*          halt_p  = (float*)alloc(4096 * 4);
  float*          halted  = (float*)alloc(4096 * 4);
  unsigned int*   flag    = (unsigned int*)alloc(16 * 4);
  float*          outF    = (float*)d_out;
  const float*    w1b     = int_w1 + 512 * 512;   // bottom half of int_w1

  // merged prep: dec_w transpose + 3 small transposes + gather + flag zero
  hipLaunchKernelGGL(kPrep, dim3(6240), dim3(256), 0, stream,
                     dec_w, dec_wT, enc_w, int_w1, int_w2, enc_wT, w1T, w2T,
                     ids, embed, bufB, flag);

  // encode: fused GEMM+gelu+LN (+halt init, pool partials)
  hipLaunchKernelGGL((kGemmLN<1>), dim3(256), dim3(512), 0, stream,
                     bufB, enc_wT, enc_b, ln_es, ln_eb,
                     (const float*)nullptr, (const float*)nullptr,
                     state, state_b, part, halt_p, halted);

  // 4 ACT loops: fused (controller || GEMM1) -> fused GEMM2+LN+update
  for (int l = 0; l < 4; l++){
    hipLaunchKernelGGL(kGemm64C, dim3(516), dim3(256), 0, stream,
                       state_b, w1T, r2, bufB, part,
                       idx_w, idx_b, mu_w, mu_b, sig_w, sig_b, pool_t,
                       w1b, int_b1, flag, outF + 131072000, l);
    hipLaunchKernelGGL((kGemmLN<0>), dim3(256), dim3(512), 0, stream,
                       bufB, w2T, int_b2, ln_s, ln_b, halt_w, halt_b,
                       state, state_b, part, halt_p, halted);
  }

  // decoder: 4000 blocks (32 m-tiles x 125 n-tiles), 512 threads
  hipLaunchKernelGGL(kGemmDec, dim3(4000), dim3(512), 0, stream,
                     state_b, dec_wT, dec_b, (float*)d_out);
}

// Round 20
// 481.533 us; speedup vs baseline: 3.1986x; 3.1986x over previous
//
#include <hip/hip_runtime.h>

#define DEV __device__ __forceinline__

typedef __attribute__((ext_vector_type(8))) short bf16x8;
typedef __attribute__((ext_vector_type(4))) float f32x4;

typedef const __attribute__((address_space(1))) void* gsrc_t;
typedef __attribute__((address_space(3))) void* gdst_t;

DEV void gld16(const void* g, void* l){ __builtin_amdgcn_global_load_lds((gsrc_t)g,(gdst_t)l,16,0,0); }

DEV unsigned short f2bf(float f){
  union { float f; unsigned int u; } x; x.f = f;
  unsigned int u = x.u;
  return (unsigned short)((u + 0x7fffu + ((u >> 16) & 1u)) >> 16);
}
DEV unsigned long long pack4bf(float a, float b, float c, float d){
  return (unsigned long long)f2bf(a)
       | ((unsigned long long)f2bf(b) << 16)
       | ((unsigned long long)f2bf(c) << 32)
       | ((unsigned long long)f2bf(d) << 48);
}
DEV float gelu_t(float x){
  float u = 0.7978845608028654f * (x + 0.044715f * x * x * x);
  return 0.5f * x * (1.0f + tanhf(u));
}
DEV float sigmoidf_(float x){ return 1.0f / (1.0f + expf(-x)); }

DEV void BAR_TOP(){ __builtin_amdgcn_s_barrier(); asm volatile("" ::: "memory"); }
DEV void BAR_END(){
  __builtin_amdgcn_sched_barrier(0);
  asm volatile("s_waitcnt lgkmcnt(0)" ::: "memory");
  __builtin_amdgcn_s_barrier();
  asm volatile("" ::: "memory");
}

// ---------------- merged prep: dec_w transpose (4000) + 3x 512^2 transpose (192)
// + embedding gather (2048 blocks, 2 rows each). Pure independent work.
__global__ __launch_bounds__(256) void kPrep(const float* __restrict__ dec_w,
                                             unsigned short* __restrict__ dec_wT,
                                             const float* __restrict__ s0, const float* __restrict__ s1,
                                             const float* __restrict__ s2,
                                             unsigned short* __restrict__ d0, unsigned short* __restrict__ d1,
                                             unsigned short* __restrict__ d2,
                                             const int* __restrict__ ids,
                                             const float* __restrict__ embed,
                                             unsigned short* __restrict__ E){
  __shared__ float t[64][65];
  const int bid = blockIdx.x, tid = threadIdx.x;
  if (bid < 4000){
    int n0 = (bid % 500) * 64, k0 = (bid / 500) * 64;
    #pragma unroll
    for (int i = 0; i < 16; i++){
      int idx = i * 256 + tid; int r = idx >> 6, c = idx & 63;
      t[r][c] = dec_w[(size_t)(k0 + r) * 32000 + n0 + c];
    }
    __syncthreads();
    #pragma unroll
    for (int i = 0; i < 16; i++){
      int idx = i * 256 + tid; int r = idx >> 6, c = idx & 63;
      dec_wT[(size_t)(n0 + r) * 512 + k0 + c] = f2bf(t[c][r]);
    }
  } else if (bid < 4192){
    int rel = bid - 4000;
    int z = rel >> 6, rem = rel & 63;
    const float* W = (z == 0) ? s0 : (z == 1) ? s1 : s2;
    unsigned short* D = (z == 0) ? d0 : (z == 1) ? d1 : d2;
    int n0 = (rem & 7) * 64, k0 = (rem >> 3) * 64;
    #pragma unroll
    for (int i = 0; i < 16; i++){
      int idx = i * 256 + tid; int r = idx >> 6, c = idx & 63;
      t[r][c] = W[(size_t)(k0 + r) * 512 + n0 + c];
    }
    __syncthreads();
    #pragma unroll
    for (int i = 0; i < 16; i++){
      int idx = i * 256 + tid; int r = idx >> 6, c = idx & 63;
      D[(size_t)(n0 + r) * 512 + k0 + c] = f2bf(t[c][r]);
    }
  } else {
    int idx = bid - 4192;                 // 0..2047, two rows per block
    int row = idx * 2 + (tid >> 7);
    int t2  = tid & 127;
    int id = ids[row];
    float4 v = ((const float4*)(embed + (size_t)id * 512))[t2];
    *(unsigned long long*)(E + (size_t)row * 512 + t2 * 4) = pack4bf(v.x, v.y, v.z, v.w);
  }
}

// ---------------- fused 16x512 GEMM + (gelu) + LN + (ACT update) + pooling partials
// Grid 256 blocks (1/CU). A-tile staged by wave 0 (1 gld16); B by all (4 gld16).
template<int ENC>
__global__ __launch_bounds__(512) void kGemmLN(
    const unsigned short* __restrict__ A, const unsigned short* __restrict__ BT,
    const float* __restrict__ bias, const float* __restrict__ lns, const float* __restrict__ lnb,
    const float* __restrict__ hw, const float* __restrict__ hb,
    float* __restrict__ st, unsigned short* __restrict__ stb,
    float* __restrict__ part, float* __restrict__ halt_p, float* __restrict__ halted){
  __shared__ alignas(16) unsigned short lA[2][16 * 32];
  __shared__ alignas(16) unsigned short lB[2][512 * 32];
  __shared__ float pS[8][16], pQ[8][16], pH[8][16];
  __shared__ float sMean[16], sRs[16], sFac[16];
  const int tid = threadIdx.x, w = tid >> 6, lane = tid & 63;
  const int q = lane >> 4, c = lane & 15, lk8 = q * 8;
  const int r0 = blockIdx.x * 16;
  const int br = tid >> 2, bk = (tid & 3) * 8;
  f32x4 acc[4] = {};

  auto STAGE = [&](int buf, int k0){
    if (w == 0)
      gld16(A + (size_t)(r0 + (lane >> 2)) * 512 + k0 + (lane & 3) * 8, &lA[buf][lane * 8]);
    #pragma unroll
    for (int i = 0; i < 4; i++)
      gld16(BT + (size_t)(i * 128 + br) * 512 + k0 + bk, &lB[buf][(i * 512 + tid) * 8]);
  };

  STAGE(0, 0);
  #pragma unroll
  for (int t = 0; t < 16; t++){
    if (t < 15){
      STAGE((t + 1) & 1, (t + 1) * 32);
      if (w == 0) asm volatile("s_waitcnt vmcnt(5)" ::: "memory");
      else        asm volatile("s_waitcnt vmcnt(4)" ::: "memory");
    } else {
      asm volatile("s_waitcnt vmcnt(0)" ::: "memory");
    }
    BAR_TOP();
    bf16x8 af = *(const bf16x8*)&lA[t & 1][c * 32 + lk8];
    bf16x8 bfv[4];
    #pragma unroll
    for (int n = 0; n < 4; n++)
      bfv[n] = *(const bf16x8*)&lB[t & 1][(w * 64 + n * 16 + c) * 32 + lk8];
    #pragma unroll
    for (int n = 0; n < 4; n++)
      acc[n] = __builtin_amdgcn_mfma_f32_16x16x32_bf16(af, bfv[n], acc[n], 0, 0, 0);
    BAR_END();
  }

  // ---- bias (+gelu)
  #pragma unroll
  for (int n = 0; n < 4; n++){
    float bcol = bias[w * 64 + n * 16 + c];
    #pragma unroll
    for (int r = 0; r < 4; r++){
      float v = acc[n][r] + bcol;
      if (ENC) v = gelu_t(v);
      acc[n][r] = v;
    }
  }
  // ---- LN stats (16 rows)
  float rS[4], rQ[4];
  #pragma unroll
  for (int r = 0; r < 4; r++){
    float s = 0.f, s2 = 0.f;
    #pragma unroll
    for (int n = 0; n < 4; n++){ float v = acc[n][r]; s += v; s2 += v * v; }
    rS[r] = s; rQ[r] = s2;
  }
  #pragma unroll
  for (int mask = 1; mask < 16; mask <<= 1)
    #pragma unroll
    for (int r = 0; r < 4; r++){
      rS[r] += __shfl_xor(rS[r], mask);
      rQ[r] += __shfl_xor(rQ[r], mask);
    }
  if (c == 0)
    #pragma unroll
    for (int r = 0; r < 4; r++){ pS[w][q * 4 + r] = rS[r]; pQ[w][q * 4 + r] = rQ[r]; }
  __syncthreads();
  if (tid < 16){
    float s = 0.f, s2 = 0.f;
    #pragma unroll
    for (int v = 0; v < 8; v++){ s += pS[v][tid]; s2 += pQ[v][tid]; }
    float mean = s * (1.f / 512.f);
    float var  = s2 * (1.f / 512.f) - mean * mean;
    sMean[tid] = mean; sRs[tid] = rsqrtf(var + 1e-5f);
    if (ENC){ halt_p[r0 + tid] = 0.f; halted[r0 + tid] = 0.f; }
  }
  __syncthreads();
  float lnsv[4], lnbv[4];
  #pragma unroll
  for (int n = 0; n < 4; n++){ lnsv[n] = lns[w * 64 + n * 16 + c]; lnbv[n] = lnb[w * 64 + n * 16 + c]; }
  #pragma unroll
  for (int r = 0; r < 4; r++){
    int row = q * 4 + r;
    float mu = sMean[row], rs = sRs[row];
    #pragma unroll
    for (int n = 0; n < 4; n++)
      acc[n][r] = (acc[n][r] - mu) * rs * lnsv[n] + lnbv[n];
  }

  float sold[4][4];
  if (!ENC){
    float hwv[4];
    #pragma unroll
    for (int n = 0; n < 4; n++) hwv[n] = hw[w * 64 + n * 16 + c];
    #pragma unroll
    for (int r = 0; r < 4; r++){
      int row = q * 4 + r;
      #pragma unroll
      for (int n = 0; n < 4; n++)
        sold[n][r] = st[(size_t)(r0 + row) * 512 + w * 64 + n * 16 + c];
    }
    float rH[4];
    #pragma unroll
    for (int r = 0; r < 4; r++){
      float d = 0.f;
      #pragma unroll
      for (int n = 0; n < 4; n++) d += (sold[n][r] + acc[n][r]) * hwv[n];
      rH[r] = d;
    }
    #pragma unroll
    for (int mask = 1; mask < 16; mask <<= 1)
      #pragma unroll
      for (int r = 0; r < 4; r++) rH[r] += __shfl_xor(rH[r], mask);
    if (c == 0)
      #pragma unroll
      for (int r = 0; r < 4; r++) pH[w][q * 4 + r] = rH[r];
    __syncthreads();
    if (tid < 16){
      float d = 0.f;
      #pragma unroll
      for (int v = 0; v < 8; v++) d += pH[v][tid];
      float hd = halted[r0 + tid];
      float p  = sigmoidf_(d + hb[0]);
      float hp = halt_p[r0 + tid] + p * (1.f - hd);
      halt_p[r0 + tid] = hp;
      halted[r0 + tid] = (hp > 0.99f) ? 1.f : 0.f;
      sFac[tid] = 1.f - hd;
    }
    __syncthreads();
    #pragma unroll
    for (int r = 0; r < 4; r++){
      float f = sFac[q * 4 + r];
      #pragma unroll
      for (int n = 0; n < 4; n++)
        acc[n][r] = sold[n][r] + f * acc[n][r];
    }
  }

  // ---- write state (fp32 + bf16)
  #pragma unroll
  for (int r = 0; r < 4; r++){
    int row = r0 + q * 4 + r;
    #pragma unroll
    for (int n = 0; n < 4; n++){
      int col = w * 64 + n * 16 + c;
      float v = acc[n][r];
      st [(size_t)row * 512 + col] = v;
      stb[(size_t)row * 512 + col] = f2bf(v);
    }
  }
  // ---- pooled partial sums over this block's 16 rows
  #pragma unroll
  for (int n = 0; n < 4; n++){
    float s = 0.f;
    #pragma unroll
    for (int r = 0; r < 4; r++) s += acc[n][r];
    s += __shfl_xor(s, 16);
    s += __shfl_xor(s, 32);
    if (q == 0) part[(size_t)blockIdx.x * 512 + w * 64 + n * 16 + c] = s;
  }
}

// ---------------- 64x64-tile GEMM1: C = gelu(A@BT + r2[row>>10]) -> bf16, dbuf pipeline
__global__ __launch_bounds__(256) void kGemm64(const unsigned short* __restrict__ A,
                                               const unsigned short* __restrict__ BT,
                                               const float* __restrict__ rb,
                                               unsigned short* __restrict__ C){
  __shared__ alignas(16) unsigned short lA[2][64 * 32];
  __shared__ alignas(16) unsigned short lB[2][64 * 32];
  const int tid = threadIdx.x, w = tid >> 6, lane = tid & 63;
  const int q = lane >> 4, c = lane & 15, lk8 = q * 8;
  const int wm = w >> 1, wn = w & 1;
  const int m0 = blockIdx.y * 64, n0 = blockIdx.x * 64;
  const int sr = tid >> 2, sk = (tid & 3) * 8;
  f32x4 acc[2][2] = {};

  auto STAGE = [&](int buf, int k0){
    gld16(A  + (size_t)(m0 + sr) * 512 + k0 + sk, &lA[buf][tid * 8]);
    gld16(BT + (size_t)(n0 + sr) * 512 + k0 + sk, &lB[buf][tid * 8]);
  };

  STAGE(0, 0);
  #pragma unroll
  for (int t = 0; t < 16; t++){
    if (t < 15){
      STAGE((t + 1) & 1, (t + 1) * 32);
      asm volatile("s_waitcnt vmcnt(2)" ::: "memory");
    } else {
      asm volatile("s_waitcnt vmcnt(0)" ::: "memory");
    }
    BAR_TOP();
    bf16x8 af[2], bfv[2];
    #pragma unroll
    for (int m = 0; m < 2; m++) af[m]  = *(const bf16x8*)&lA[t & 1][(wm * 32 + m * 16 + c) * 32 + lk8];
    #pragma unroll
    for (int n = 0; n < 2; n++) bfv[n] = *(const bf16x8*)&lB[t & 1][(wn * 32 + n * 16 + c) * 32 + lk8];
    #pragma unroll
    for (int m = 0; m < 2; m++)
      #pragma unroll
      for (int n = 0; n < 2; n++)
        acc[m][n] = __builtin_amdgcn_mfma_f32_16x16x32_bf16(af[m], bfv[n], acc[m][n], 0, 0, 0);
    BAR_END();
  }

  #pragma unroll
  for (int m = 0; m < 2; m++)
    #pragma unroll
    for (int n = 0; n < 2; n++)
      #pragma unroll
      for (int r = 0; r < 4; r++){
        int row = m0 + wm * 32 + m * 16 + q * 4 + r;
        int col = n0 + wn * 32 + n * 16 + c;
        float v = acc[m][n][r] + rb[((row >> 10) << 9) + col];
        C[(size_t)row * 512 + col] = f2bf(gelu_t(v));
      }
}

// ---------------- decoder GEMM v9 (measured best): 128x256, 512 thr, 3 bufs, vmcnt(3),
// one barrier/phase, compiler-scheduled ds_read->MFMA, early STAGE, T2 swizzle, setprio,
// m-inner + bijective XCD swizzle, nontemporal fp32 stores + bias.
__global__ __launch_bounds__(512) void kGemmDec(const unsigned short* __restrict__ A,
                                                const unsigned short* __restrict__ BT,
                                                const float* __restrict__ bias,
                                                float* __restrict__ C){
  __shared__ alignas(16) unsigned short lA[3][128 * 32];   // 8 KB each
  __shared__ alignas(16) unsigned short lB[3][256 * 32];   // 16 KB each
  const int tid = threadIdx.x, w = tid >> 6, lane = tid & 63;
  const int wm = w >> 2, wn = w & 3;           // 2 x 4 wave grid, per-wave 64x64
  const int c = lane & 15, q = lane >> 4;
  const int rk8 = (q ^ ((c >> 1) & 3)) * 8;    // swizzled read chunk (elems)
  int flat = blockIdx.x;                       // 0..3999
  flat = (flat & 7) * 500 + (flat >> 3);       // bijective XCD swizzle (4000 = 8*500)
  const int m0 = (flat & 31) * 128;            // m-inner: 32 consecutive share one B-panel
  const int n0 = (flat >> 5) * 256;
  const int srow  = tid >> 2;                  // 0..127
  const int skoff = ((tid & 3) ^ ((srow >> 1) & 3)) * 8;  // pre-swizzled source chunk
  const int sdst  = srow * 32 + (tid & 3) * 8;            // linear LDS dest
  f32x4 acc[4][4] = {};

  auto STAGE = [&](int buf, int k0){
    gld16(A  + (size_t)(m0 + srow) * 512 + k0 + skoff,       &lA[buf][sdst]);
    gld16(BT + (size_t)(n0 + srow) * 512 + k0 + skoff,       &lB[buf][sdst]);
    gld16(BT + (size_t)(n0 + 128 + srow) * 512 + k0 + skoff, &lB[buf][128 * 32 + sdst]);
  };

  STAGE(0, 0);
  STAGE(1, 32);
  for (int t = 0; t < 16; t++){
    const int buf = t % 3;
    if (t < 15) asm volatile("s_waitcnt vmcnt(3)" ::: "memory");
    else        asm volatile("s_waitcnt vmcnt(0)" ::: "memory");
    __builtin_amdgcn_s_barrier();
    asm volatile("" ::: "memory");
    if (t < 14) STAGE((t + 2) % 3, (t + 2) * 32);   // loads in flight early
    bf16x8 af[4], bfr[4];
    #pragma unroll
    for (int mf = 0; mf < 4; mf++)
      af[mf] = *(const bf16x8*)&lA[buf][(wm * 64 + mf * 16 + c) * 32 + rk8];
    #pragma unroll
    for (int nf = 0; nf < 4; nf++)
      bfr[nf] = *(const bf16x8*)&lB[buf][(wn * 64 + nf * 16 + c) * 32 + rk8];
    // no manual lgkmcnt/sched_barrier: compiler emits fine-grained waits
    __builtin_amdgcn_s_setprio(1);
    #pragma unroll
    for (int mf = 0; mf < 4; mf++)
      #pragma unroll
      for (int nf = 0; nf < 4; nf++)
        acc[mf][nf] = __builtin_amdgcn_mfma_f32_16x16x32_bf16(af[mf], bfr[nf], acc[mf][nf], 0, 0, 0);
    __builtin_amdgcn_s_setprio(0);
  }

  #pragma unroll
  for (int mf = 0; mf < 4; mf++){
    int rbase = m0 + wm * 64 + mf * 16 + q * 4;
    #pragma unroll
    for (int nf = 0; nf < 4; nf++){
      int col = n0 + wn * 64 + nf * 16 + c;
      float bcol = bias[col];
      #pragma unroll
      for (int r = 0; r < 4; r++)
        __builtin_nontemporal_store(acc[mf][nf][r] + bcol,
                                    &C[(size_t)(rbase + r) * 32000 + col]);
    }
  }
}

// ---------------- controller: coalesced row-sweep GEMVs (64 pooled chunks)
__global__ __launch_bounds__(512) void kCtl(const float* __restrict__ part,
                                            const float* __restrict__ idx_w, const float* __restrict__ idx_b,
                                            const float* __restrict__ mu_w, const float* __restrict__ mu_b,
                                            const float* __restrict__ sig_w, const float* __restrict__ sig_b,
                                            const float* __restrict__ pool_table,
                                            const float* __restrict__ w1b, const float* __restrict__ int_b1,
                                            float* __restrict__ r2, float* __restrict__ outIdx, int loop){
  __shared__ float xs[512];
  __shared__ float red[512];
  __shared__ float red2[512];
  __shared__ float evals[64];
  __shared__ float sc[4];
  int b = blockIdx.x, tid = threadIdx.x;

  float s = 0.f;
  #pragma unroll 8
  for (int c2 = 0; c2 < 64; c2++) s += part[(size_t)(b * 64 + c2) * 512 + tid];
  xs[tid] = s * (1.0f / 1024.0f);
  __syncthreads();

  float a = idx_b[tid];
  #pragma unroll 32
  for (int i = 0; i < 512; i++)
    a = fmaf(xs[i], idx_w[(size_t)i * 512 + tid], a);
  float hv = gelu_t(a);
  red[tid]  = hv * mu_w[tid];
  red2[tid] = hv * sig_w[tid];
  __syncthreads();
  for (int off2 = 256; off2 > 0; off2 >>= 1){
    if (tid < off2){ red[tid] += red[tid + off2]; red2[tid] += red2[tid + off2]; }
    __syncthreads();
  }
  if (tid == 0){
    float mu = sigmoidf_(red[0] + mu_b[0]);
    float sg = log1pf(expf(red2[0] + sig_b[0])) + 1e-4f;
    float center = mu * 250000.0f;
    int stt = (int)floorf(center - 32.0f);
    stt = stt < 0 ? 0 : (stt > 250000 - 64 ? 250000 - 64 : stt);
    sc[0] = mu; sc[1] = sg; sc[2] = (float)stt;
    outIdx[b * 4 + loop] = (float)stt;
  }
  __syncthreads();
  if (tid < 64){
    float pos = (sc[2] + (float)tid) * (1.0f / 250000.0f);
    float z = (pos - sc[0]) / sc[1];
    evals[tid] = expf(-0.5f * z * z);
  }
  __syncthreads();
  if (tid == 0){
    float wsum = 0.f;
    for (int j = 0; j < 64; j++) wsum += evals[j];
    sc[3] = wsum;
  }
  __syncthreads();
  int stt = (int)sc[2];
  float r = 0.f;
  #pragma unroll 8
  for (int j = 0; j < 64; j++)
    r = fmaf(evals[j], pool_table[(size_t)(stt + j) * 512 + tid], r);
  r /= sc[3];
  __syncthreads();
  xs[tid] = r;
  __syncthreads();
  float a2 = int_b1[tid];
  #pragma unroll 32
  for (int i = 0; i < 512; i++)
    a2 = fmaf(xs[i], w1b[(size_t)i * 512 + tid], a2);
  r2[(size_t)b * 512 + tid] = a2;
}

extern "C" void kernel_launch(void* const* d_in, const int* in_sizes, int n_in,
                              void* d_out, int out_size, void* d_ws, size_t ws_size,
                              hipStream_t stream){
  (void)in_sizes; (void)n_in; (void)out_size; (void)ws_size;
  const int*   ids    = (const int*)  d_in[0];
  const float* embed  = (const float*)d_in[1];
  const float* enc_w  = (const float*)d_in[2];
  const float* enc_b  = (const float*)d_in[3];
  const float* ln_es  = (const float*)d_in[4];
  const float* ln_eb  = (const float*)d_in[5];
  const float* idx_w  = (const float*)d_in[6];
  const float* idx_b  = (const float*)d_in[7];
  const float* mu_w   = (const float*)d_in[8];
  const float* mu_b   = (const float*)d_in[9];
  const float* sig_w  = (const float*)d_in[10];
  const float* sig_b  = (const float*)d_in[11];
  const float* pool_t = (const float*)d_in[12];
  const float* int_w1 = (const float*)d_in[13];
  const float* int_b1 = (const float*)d_in[14];
  const float* int_w2 = (const float*)d_in[15];
  const float* int_b2 = (const float*)d_in[16];
  const float* ln_s   = (const float*)d_in[17];
  const float* ln_b   = (const float*)d_in[18];
  const float* halt_w = (const float*)d_in[19];
  const float* halt_b = (const float*)d_in[20];
  const float* dec_w  = (const float*)d_in[21];
  const float* dec_b  = (const float*)d_in[22];

  char* ws = (char*)d_ws;
  size_t off = 0;
  auto alloc = [&](size_t bytes)->char*{
    char* p = ws + off; off += (bytes + 255) & ~(size_t)255; return p;
  };
  unsigned short* dec_wT  = (unsigned short*)alloc(32000ull * 512 * 2);
  unsigned short* enc_wT  = (unsigned short*)alloc(512ull * 512 * 2);
  unsigned short* w1T     = (unsigned short*)alloc(512ull * 512 * 2);
  unsigned short* w2T     = (unsigned short*)alloc(512ull * 512 * 2);
  unsigned short* bufB    = (unsigned short*)alloc(4096ull * 512 * 2);  // E / G (bf16)
  float*          state   = (float*)alloc(4096ull * 512 * 4);
  unsigned short* state_b = (unsigned short*)alloc(4096ull * 512 * 2);
  float*          part    = (float*)alloc(256ull * 512 * 4);
  float*          r2      = (float*)alloc(4ull * 512 * 4);
  float*          halt_p  = (float*)alloc(4096 * 4);
  float*          halted  = (float*)alloc(4096 * 4);
  float*          outF    = (float*)d_out;

  // merged prep: dec_w transpose + 3 small transposes + gather
  hipLaunchKernelGGL(kPrep, dim3(6240), dim3(256), 0, stream,
                     dec_w, dec_wT, enc_w, int_w1, int_w2, enc_wT, w1T, w2T,
                     ids, embed, bufB);

  // encode: fused GEMM+gelu+LN (+halt init, pool partials)
  hipLaunchKernelGGL((kGemmLN<1>), dim3(256), dim3(512), 0, stream,
                     bufB, enc_wT, enc_b, ln_es, ln_eb,
                     (const float*)nullptr, (const float*)nullptr,
                     state, state_b, part, halt_p, halted);

  // 4 ACT loops: ctl -> GEMM1 -> fused GEMM2+LN+update
  for (int l = 0; l < 4; l++){
    hipLaunchKernelGGL(kCtl, dim3(4), dim3(512), 0, stream, part, idx_w, idx_b,
                       mu_w, mu_b, sig_w, sig_b, pool_t,
                       int_w1 + 512 * 512, int_b1,
                       r2, outF + 131072000, l);
    hipLaunchKernelGGL(kGemm64, dim3(8, 64), dim3(256), 0, stream,
                       state_b, w1T, r2, bufB);
    hipLaunchKernelGGL((kGemmLN<0>), dim3(256), dim3(512), 0, stream,
                       bufB, w2T, int_b2, ln_s, ln_b, halt_w, halt_b,
                       state, state_b, part, halt_p, halted);
  }

  // decoder: 4000 blocks (32 m-tiles x 125 n-tiles), 512 threads
  hipLaunchKernelGGL(kGemmDec, dim3(4000), dim3(512), 0, stream,
                     state_b, dec_wT, dec_b, (float*)d_out);
}